// Round 3
// baseline (321.148 us; speedup 1.0000x reference)
//
#include <hip/hip_runtime.h>

// Adder v4: v3 structure (float4, two-level carry-lookahead, 4 tiles/wave,
// one-shot waves) with ONE change: non-temporal output stores.
//
// Rationale: per dispatch the kernel reads 268 MB (a,b) and writes 134 MB.
// rocprof shows FETCH ~= 134 MB: half the input reads miss L3 because the
// write-allocating output stream evicts input lines from the 256 MB L3.
// nt stores stop the output from polluting L3, so inputs stay resident
// across the benchmark's repeated dispatches -> HBM fetch collapses.
//
// Carry math unchanged from v3 (verified): in-lane ripple -> block G/P,
// __ballot packs 4 rows x 16 blocks, C = ((P|G)+G) ^ (P|G) ^ G in LSB-first
// order gives per-block carry-in. Digits are exact small ints in fp32.

typedef float v4f __attribute__((ext_vector_type(4)));

__device__ __forceinline__ v4f add_tile(const v4f av, const v4f bv,
                                        const int k, const int pos) {
    const float s0 = av.x + bv.x;   // most significant of the lane's 4
    const float s1 = av.y + bv.y;
    const float s2 = av.z + bv.z;
    const float s3 = av.w + bv.w;   // least significant

    // block generate (ripple, cin=0) and propagate
    float gc = (s3 >= 10.0f) ? 1.0f : 0.0f;
    gc = (s2 + gc >= 10.0f) ? 1.0f : 0.0f;
    gc = (s1 + gc >= 10.0f) ? 1.0f : 0.0f;
    gc = (s0 + gc >= 10.0f) ? 1.0f : 0.0f;
    const bool Gb = (gc != 0.0f);
    const bool Pb = (s0 == 9.0f) & (s1 == 9.0f) & (s2 == 9.0f) & (s3 == 9.0f);

    // cross-lane 16-block lookahead per row
    const unsigned long long g_mask = __ballot(Gb);
    const unsigned long long p_mask = __ballot(Pb);
    unsigned int g16 = (unsigned int)(g_mask >> (k * 16)) & 0xFFFFu;
    unsigned int p16 = (unsigned int)(p_mask >> (k * 16)) & 0xFFFFu;
    g16 = __brev(g16) >> 16;                 // bit blk -> bit (15-blk), LSB-first
    p16 = __brev(p16) >> 16;
    const unsigned int pg  = p16 | g16;
    const unsigned int c16 = (pg + g16) ^ pg ^ g16;   // carry-in per position
    const float cin = (float)((c16 >> pos) & 1u);

    // in-lane ripple with recovered block carry-in
    const float u3 = s3 + cin; const float c3 = (u3 >= 10.0f) ? 1.0f : 0.0f;
    const float u2 = s2 + c3;  const float c2 = (u2 >= 10.0f) ? 1.0f : 0.0f;
    const float u1 = s1 + c2;  const float c1 = (u1 >= 10.0f) ? 1.0f : 0.0f;
    const float u0 = s0 + c1;  const float c0 = (u0 >= 10.0f) ? 1.0f : 0.0f;

    v4f dv;
    dv.x = u0 - 10.0f * c0;
    dv.y = u1 - 10.0f * c1;
    dv.z = u2 - 10.0f * c2;
    dv.w = u3 - 10.0f * c3;
    return dv;
}

__global__ __launch_bounds__(256) void adder_kernel(
    const v4f* __restrict__ a,
    const v4f* __restrict__ b,
    v4f* __restrict__ out,
    long long n_tiles)   // tiles of 4 rows (64 float4s each)
{
    const int lane = (int)(threadIdx.x & 63);
    const int k    = lane >> 4;          // row within tile
    const int pos  = 15 - (lane & 15);   // LSB-first block position

    const long long wave_id = (long long)blockIdx.x * 4 + (threadIdx.x >> 6);
    const long long t0 = wave_id * 4;    // 4 tiles per wave
    if (t0 >= n_tiles) return;

    if (t0 + 4 <= n_tiles) {
        const long long i0 = t0 * 64 + lane;
        const v4f a0 = a[i0];
        const v4f b0 = b[i0];
        const v4f a1 = a[i0 + 64];
        const v4f b1 = b[i0 + 64];
        const v4f a2 = a[i0 + 128];
        const v4f b2 = b[i0 + 128];
        const v4f a3 = a[i0 + 192];
        const v4f b3 = b[i0 + 192];

        __builtin_nontemporal_store(add_tile(a0, b0, k, pos), &out[i0]);
        __builtin_nontemporal_store(add_tile(a1, b1, k, pos), &out[i0 + 64]);
        __builtin_nontemporal_store(add_tile(a2, b2, k, pos), &out[i0 + 128]);
        __builtin_nontemporal_store(add_tile(a3, b3, k, pos), &out[i0 + 192]);
    } else {
        // tail (wave-uniform branch; all 64 lanes participate in ballots)
        for (long long t = t0; t < n_tiles; ++t) {
            const long long i = t * 64 + lane;
            __builtin_nontemporal_store(add_tile(a[i], b[i], k, pos), &out[i]);
        }
    }
}

extern "C" void kernel_launch(void* const* d_in, const int* in_sizes, int n_in,
                              void* d_out, int out_size, void* d_ws, size_t ws_size,
                              hipStream_t stream) {
    const v4f* a = (const v4f*)d_in[0];
    const v4f* b = (const v4f*)d_in[1];
    v4f* out = (v4f*)d_out;

    const long long n_rows  = (long long)in_sizes[0] / 64;   // 524288
    const long long n_tiles = (n_rows + 3) / 4;              // 131072
    const long long n_waves = (n_tiles + 3) / 4;             // 32768 (4 tiles/wave)
    const long long blocks  = (n_waves + 3) / 4;             // 8192 (4 waves/block)
    adder_kernel<<<(int)blocks, 256, 0, stream>>>(a, b, out, n_tiles);
}

// Round 4
// 314.496 us; speedup vs baseline: 1.0212x; 1.0212x over previous
//
#include <hip/hip_runtime.h>

// Adder v5: persistent grid-stride kernel with depth-2 software pipelining.
// float4 layout, two-level carry-lookahead (unchanged, verified since v2).
//
// Structure: 2048 blocks x 256 threads (8 blocks/CU on 256 CUs), each lane
// owns 16 float4s per array at stride 524288. Pipelined: issue iteration
// i+1's (a,b) loads BEFORE computing/storing iteration i, so HBM latency
// hides under compute+store and waves never retire (no wave-churn ramp).
// Normal (cached) stores -- v4 proved nt stores only hurt (-14%, FETCH
// unchanged: memory-side L3 is not bypassable).
//
// Carry math: 16 lanes per row, 4 digits/lane. In-lane ripple -> block
// generate Gb; block propagate Pb = all four sums == 9 (mutually
// exclusive). __ballot packs 4 rows x 16 blocks; each 16-lane group
// extracts its row's 16 bits, reverses to LSB-first, and applies
// C = ((P|G)+G) ^ (P|G) ^ G  (carries of X+G with X=P|G obey
// c_{i+1} = G_i | (P_i & c_i)). Digits are exact small ints in fp32.

typedef float v4f __attribute__((ext_vector_type(4)));

__device__ __forceinline__ v4f add_tile(const v4f av, const v4f bv,
                                        const int k, const int pos) {
    const float s0 = av.x + bv.x;   // most significant of the lane's 4
    const float s1 = av.y + bv.y;
    const float s2 = av.z + bv.z;
    const float s3 = av.w + bv.w;   // least significant

    // block generate (ripple, cin=0) and propagate
    float gc = (s3 >= 10.0f) ? 1.0f : 0.0f;
    gc = (s2 + gc >= 10.0f) ? 1.0f : 0.0f;
    gc = (s1 + gc >= 10.0f) ? 1.0f : 0.0f;
    gc = (s0 + gc >= 10.0f) ? 1.0f : 0.0f;
    const bool Gb = (gc != 0.0f);
    const bool Pb = (s0 == 9.0f) & (s1 == 9.0f) & (s2 == 9.0f) & (s3 == 9.0f);

    // cross-lane 16-block lookahead per row
    const unsigned long long g_mask = __ballot(Gb);
    const unsigned long long p_mask = __ballot(Pb);
    unsigned int g16 = (unsigned int)(g_mask >> (k * 16)) & 0xFFFFu;
    unsigned int p16 = (unsigned int)(p_mask >> (k * 16)) & 0xFFFFu;
    g16 = __brev(g16) >> 16;                 // bit blk -> bit (15-blk), LSB-first
    p16 = __brev(p16) >> 16;
    const unsigned int pg  = p16 | g16;
    const unsigned int c16 = (pg + g16) ^ pg ^ g16;   // carry-in per position
    const float cin = (float)((c16 >> pos) & 1u);

    // in-lane ripple with recovered block carry-in
    const float u3 = s3 + cin; const float c3 = (u3 >= 10.0f) ? 1.0f : 0.0f;
    const float u2 = s2 + c3;  const float c2 = (u2 >= 10.0f) ? 1.0f : 0.0f;
    const float u1 = s1 + c2;  const float c1 = (u1 >= 10.0f) ? 1.0f : 0.0f;
    const float u0 = s0 + c1;  const float c0 = (u0 >= 10.0f) ? 1.0f : 0.0f;

    v4f dv;
    dv.x = u0 - 10.0f * c0;
    dv.y = u1 - 10.0f * c1;
    dv.z = u2 - 10.0f * c2;
    dv.w = u3 - 10.0f * c3;
    return dv;
}

__global__ __launch_bounds__(256) void adder_kernel(
    const v4f* __restrict__ a,
    const v4f* __restrict__ b,
    v4f* __restrict__ out,
    long long n_v4)   // total float4 count (= n_rows * 16)
{
    const int lane = (int)(threadIdx.x & 63);
    const int k    = lane >> 4;          // row within the wave's 4-row group
    const int pos  = 15 - (lane & 15);   // LSB-first block position

    const long long base   = (long long)blockIdx.x * blockDim.x + threadIdx.x;
    const long long stride = (long long)gridDim.x * blockDim.x;

    if (base >= n_v4) return;

    // depth-2 pipeline: current tile in (ca,cb), next tile prefetched
    // before current is computed/stored.
    v4f ca = a[base];
    v4f cb = b[base];
    long long idx  = base;
    long long next = base + stride;

    while (next < n_v4) {
        const v4f na = a[next];              // prefetch iteration i+1
        const v4f nb = b[next];
        out[idx] = add_tile(ca, cb, k, pos); // compute+store iteration i
        ca = na; cb = nb;
        idx = next; next += stride;
    }
    out[idx] = add_tile(ca, cb, k, pos);
}

extern "C" void kernel_launch(void* const* d_in, const int* in_sizes, int n_in,
                              void* d_out, int out_size, void* d_ws, size_t ws_size,
                              hipStream_t stream) {
    const v4f* a = (const v4f*)d_in[0];
    const v4f* b = (const v4f*)d_in[1];
    v4f* out = (v4f*)d_out;

    const long long n_rows = (long long)in_sizes[0] / 64;   // 524288
    const long long n_v4   = n_rows * 16;                   // 8388608 float4s
    const int blocks = 2048;   // 8 blocks/CU x 256 CU; 16 iters/lane, no tail
    adder_kernel<<<blocks, 256, 0, stream>>>(a, b, out, n_v4);
}

// Round 6
// 307.797 us; speedup vs baseline: 1.0434x; 1.0218x over previous
//
#include <hip/hip_runtime.h>

// Adder v7 = v1 (best measured: 102 us/dispatch, 309.9 us harness, PASS).
// Reverts v6's 1024-thread blocks: correct math (pre-timing absmax 0.0) but
// intermittent post-timing launch failure in the graph harness (absmax 9.0
// == poisoned output never overwritten). 256-thread blocks are proven.
//
// Structure: one wave (64 lanes) per row, scalar dword access, one-shot
// waves (524288 waves, max request-stream parallelism -- measured fastest
// across 5 structural variants; vectorization/pipelining/nt all null or
// negative, the limiter is the memory system's service rate for this
// 2R:1W sweep, not wave code).
//
// Carry chain in closed form via ballot + 64-bit carry-lookahead:
//   g = (s >= 10) generate, p = (s == 9) propagate (mutually exclusive)
//   LSB-first: C = ((P|G)+G) ^ (P|G) ^ G  (adder identity for
//   c_{i+1} = g_i | (p_i & c_i)). Digits are exact small ints in fp32.

__global__ __launch_bounds__(256) void adder_kernel(
    const float* __restrict__ a,
    const float* __restrict__ b,
    float* __restrict__ out,
    long long n_rows)
{
    const int lane = (int)(threadIdx.x & 63);
    const long long row = (long long)blockIdx.x * 4 + (threadIdx.x >> 6);
    if (row >= n_rows) return;

    const long long idx = row * 64 + lane;   // wave: 256B contiguous
    const float s = a[idx] + b[idx];         // 0..18, exact integer

    // lane-space masks (bit l = lane l = digit index l; index 63 is LSB)
    const unsigned long long g_l = __ballot(s >= 10.0f);
    const unsigned long long p_l = __ballot(s == 9.0f);

    // reverse into LSB-first position space (position k = 63 - lane)
    const unsigned long long G  = __brevll(g_l);
    const unsigned long long P  = __brevll(p_l);
    const unsigned long long PG = P | G;
    const unsigned long long C_pos = (PG + G) ^ PG ^ G;  // carry-in per position
    const unsigned long long C_l   = __brevll(C_pos);    // back to lane space

    const float cin = (float)((C_l >> lane) & 1ULL);
    const float u = s + cin;                  // 0..19
    const float carry_out = (u >= 10.0f) ? 1.0f : 0.0f;
    out[idx] = u - 10.0f * carry_out;
}

extern "C" void kernel_launch(void* const* d_in, const int* in_sizes, int n_in,
                              void* d_out, int out_size, void* d_ws, size_t ws_size,
                              hipStream_t stream) {
    const float* a = (const float*)d_in[0];
    const float* b = (const float*)d_in[1];
    float* out = (float*)d_out;

    const long long n_rows = (long long)in_sizes[0] / 64;  // 524288
    // 256 threads = 4 waves = 4 rows per block
    const int blocks = (int)((n_rows + 3) / 4);
    adder_kernel<<<blocks, 256, 0, stream>>>(a, b, out, n_rows);
}